// Round 5
// baseline (52091.034 us; speedup 1.0000x reference)
//
#include <hip/hip_runtime.h>
#include <float.h>

// Problem constants (fixed shapes from setup_inputs)
#define NN 4096      // b*n
#define DD 640       // d
#define DE 512       // embed/inner dim
#define NB 16        // LU inner panel width
#define OB 128       // LU outer block width
#define NOB (NN/OB)  // 32 outer blocks
#define SB 128       // solve block
#define NSB (NN/SB)  // 32 solve blocks

static __device__ __forceinline__ float4 ldg4(const float* p) { return *(const float4*)p; }

// ---------------------------------------------------------------------------
// 1) q = xe@Wq, k = xe@Wk  (xe = xf[:, :512], ld 640). Fused dual GEMM.
// ---------------------------------------------------------------------------
__global__ __launch_bounds__(256) void proj_gemm(
    const float* __restrict__ xf, const float* __restrict__ Wq,
    const float* __restrict__ Wk, float* __restrict__ q, float* __restrict__ kk_)
{
  __shared__ float Xs[32][68], Qs[32][68], Ks[32][68];
  const int i0 = blockIdx.x * 64, c0 = blockIdx.y * 64;
  const int t = threadIdx.x, tr = t >> 4, tc = t & 15;
  float accq[4][4] = {}, acck[4][4] = {};
  for (int kb = 0; kb < DE; kb += 32) {
    {
      int m = t >> 3, k4 = (t & 7) << 2;
      float4 v0 = ldg4(xf + (size_t)(i0 + m) * DD + kb + k4);
      float4 v1 = ldg4(xf + (size_t)(i0 + m + 32) * DD + kb + k4);
      Xs[k4+0][m] = v0.x; Xs[k4+1][m] = v0.y; Xs[k4+2][m] = v0.z; Xs[k4+3][m] = v0.w;
      Xs[k4+0][m+32] = v1.x; Xs[k4+1][m+32] = v1.y; Xs[k4+2][m+32] = v1.z; Xs[k4+3][m+32] = v1.w;
    }
    {
      int kr = t >> 3, n8 = (t & 7) << 3;
      *(float4*)&Qs[kr][n8]   = ldg4(Wq + (size_t)(kb + kr) * DE + c0 + n8);
      *(float4*)&Qs[kr][n8+4] = ldg4(Wq + (size_t)(kb + kr) * DE + c0 + n8 + 4);
      *(float4*)&Ks[kr][n8]   = ldg4(Wk + (size_t)(kb + kr) * DE + c0 + n8);
      *(float4*)&Ks[kr][n8+4] = ldg4(Wk + (size_t)(kb + kr) * DE + c0 + n8 + 4);
    }
    __syncthreads();
    #pragma unroll
    for (int kkk = 0; kkk < 32; ++kkk) {
      float a[4], bq[4], bk[4];
      *(float4*)a  = *(const float4*)&Xs[kkk][tr << 2];
      *(float4*)bq = *(const float4*)&Qs[kkk][tc << 2];
      *(float4*)bk = *(const float4*)&Ks[kkk][tc << 2];
      #pragma unroll
      for (int r = 0; r < 4; ++r)
        #pragma unroll
        for (int c = 0; c < 4; ++c) { accq[r][c] += a[r]*bq[c]; acck[r][c] += a[r]*bk[c]; }
    }
    __syncthreads();
  }
  #pragma unroll
  for (int r = 0; r < 4; ++r) {
    float* qp = q   + (size_t)(i0 + (tr<<2) + r) * DE + c0 + (tc<<2);
    float* kp = kk_ + (size_t)(i0 + (tr<<2) + r) * DE + c0 + (tc<<2);
    *(float4*)qp = make_float4(accq[r][0], accq[r][1], accq[r][2], accq[r][3]);
    *(float4*)kp = make_float4(acck[r][0], acck[r][1], acck[r][2], acck[r][3]);
  }
}

// ---------------------------------------------------------------------------
// 2) row squared norms
// ---------------------------------------------------------------------------
__global__ __launch_bounds__(256) void rownorm(
    const float* __restrict__ q, const float* __restrict__ kk_,
    float* __restrict__ q2, float* __restrict__ k2)
{
  int w = (blockIdx.x * 256 + threadIdx.x) >> 6;
  int lane = threadIdx.x & 63;
  const float* src = (w < NN) ? q : kk_;
  int row = (w < NN) ? w : w - NN;
  const float* p = src + (size_t)row * DE;
  float s = 0.f;
  for (int c = lane; c < DE; c += 64) { float v = p[c]; s += v * v; }
  for (int off = 32; off; off >>= 1) s += __shfl_down(s, off);
  if (lane == 0) { if (w < NN) q2[row] = s; else k2[row] = s; }
}

// ---------------------------------------------------------------------------
// 3) dots = (q2[i]+k2[j]-2*q@k^T)/DE
// ---------------------------------------------------------------------------
__global__ __launch_bounds__(256) void dots_gemm(
    const float* __restrict__ q, const float* __restrict__ kk_,
    const float* __restrict__ q2, const float* __restrict__ k2,
    float* __restrict__ dots)
{
  __shared__ float Qs[32][68], Ks[32][68];
  const int i0 = blockIdx.x * 64, j0 = blockIdx.y * 64;
  const int t = threadIdx.x, tr = t >> 4, tc = t & 15;
  float acc[4][4] = {};
  for (int kb = 0; kb < DE; kb += 32) {
    int m = t >> 3, k4 = (t & 7) << 2;
    {
      float4 v0 = ldg4(q + (size_t)(i0 + m) * DE + kb + k4);
      float4 v1 = ldg4(q + (size_t)(i0 + m + 32) * DE + kb + k4);
      Qs[k4+0][m] = v0.x; Qs[k4+1][m] = v0.y; Qs[k4+2][m] = v0.z; Qs[k4+3][m] = v0.w;
      Qs[k4+0][m+32] = v1.x; Qs[k4+1][m+32] = v1.y; Qs[k4+2][m+32] = v1.z; Qs[k4+3][m+32] = v1.w;
    }
    {
      float4 v0 = ldg4(kk_ + (size_t)(j0 + m) * DE + kb + k4);
      float4 v1 = ldg4(kk_ + (size_t)(j0 + m + 32) * DE + kb + k4);
      Ks[k4+0][m] = v0.x; Ks[k4+1][m] = v0.y; Ks[k4+2][m] = v0.z; Ks[k4+3][m] = v0.w;
      Ks[k4+0][m+32] = v1.x; Ks[k4+1][m+32] = v1.y; Ks[k4+2][m+32] = v1.z; Ks[k4+3][m+32] = v1.w;
    }
    __syncthreads();
    #pragma unroll
    for (int kkk = 0; kkk < 32; ++kkk) {
      float a[4], b[4];
      *(float4*)a = *(const float4*)&Qs[kkk][tr << 2];
      *(float4*)b = *(const float4*)&Ks[kkk][tc << 2];
      #pragma unroll
      for (int r = 0; r < 4; ++r)
        #pragma unroll
        for (int c = 0; c < 4; ++c) acc[r][c] += a[r]*b[c];
    }
    __syncthreads();
  }
  const float inv = 1.0f / (float)DE;
  float k2v[4]; *(float4*)k2v = ldg4(k2 + j0 + (tc<<2));
  #pragma unroll
  for (int r = 0; r < 4; ++r) {
    float q2v = q2[i0 + (tr<<2) + r];
    float o[4];
    #pragma unroll
    for (int c = 0; c < 4; ++c) o[c] = (q2v + k2v[c] - 2.0f*acc[r][c]) * inv;
    *(float4*)(dots + (size_t)(i0 + (tr<<2) + r) * NN + j0 + (tc<<2)) =
        make_float4(o[0], o[1], o[2], o[3]);
  }
}

// ---------------------------------------------------------------------------
// 4) per-row top-64 -> bit mask rows
// ---------------------------------------------------------------------------
__global__ __launch_bounds__(256) void topk_bits(
    const float* __restrict__ dots, unsigned int* __restrict__ bits)
{
  __shared__ float row[NN];
  __shared__ unsigned int b[128];
  __shared__ float rv[4]; __shared__ int ri[4];
  const int i = blockIdx.x, t = threadIdx.x;
  const float* dr = dots + (size_t)i * NN;
  for (int c = t; c < NN; c += 256) row[c] = dr[c];
  if (t < 128) b[t] = 0u;
  __syncthreads();
  for (int it = 0; it < 64; ++it) {
    float bv = -FLT_MAX; int bi = NN;
    for (int c = t; c < NN; c += 256) { float v = row[c]; if (v > bv) { bv = v; bi = c; } }
    for (int off = 32; off; off >>= 1) {
      float ov = __shfl_down(bv, off); int oi = __shfl_down(bi, off);
      if (ov > bv || (ov == bv && oi < bi)) { bv = ov; bi = oi; }
    }
    if ((t & 63) == 0) { rv[t >> 6] = bv; ri[t >> 6] = bi; }
    __syncthreads();
    if (t == 0) {
      float fv = rv[0]; int fi = ri[0];
      for (int w = 1; w < 4; ++w)
        if (rv[w] > fv || (rv[w] == fv && ri[w] < fi)) { fv = rv[w]; fi = ri[w]; }
      b[fi >> 5] |= 1u << (fi & 31);
      row[fi] = -FLT_MAX;
    }
    __syncthreads();
  }
  if (t < 128) bits[(size_t)i * 128 + t] = b[t];
}

// ---------------------------------------------------------------------------
// 5) A = I - alpha * dots * (bit(i,j)|bit(j,i)), in place over dots.
// ---------------------------------------------------------------------------
__global__ __launch_bounds__(256) void build_A(
    float* __restrict__ A, const unsigned int* __restrict__ bits,
    const float* __restrict__ alpha_p)
{
  int tid = blockIdx.x * 256 + threadIdx.x;
  int i = tid >> 10;
  int j4 = (tid & 1023) << 2;
  float alpha = alpha_p[0];
  float* p = A + (size_t)i * NN + j4;
  float4 d = *(float4*)p;
  unsigned int wrow = bits[(size_t)i * 128 + (j4 >> 5)];
  float dv[4] = {d.x, d.y, d.z, d.w}, o[4];
  #pragma unroll
  for (int u = 0; u < 4; ++u) {
    int j = j4 + u;
    unsigned int m1 = (wrow >> (j & 31)) & 1u;
    unsigned int m2 = (bits[(size_t)j * 128 + (i >> 5)] >> (i & 31)) & 1u;
    float base = (i == j) ? 1.0f : 0.0f;
    o[u] = base - ((m1 | m2) ? alpha * dv[u] : 0.0f);
  }
  *(float4*)p = make_float4(o[0], o[1], o[2], o[3]);
}

// ---------------------------------------------------------------------------
// 6) LEFT-LOOKING LU panel (NB=16 cols), partial pivoting. 1024 threads.
//    Entry: apply deferred rank-16 updates from previous panels of this
//    outer block to its own 16 columns (register-resident).
//    Factor loop: 2 barriers/column (double-buffered rv/ri/pivot-row).
//    Tail: fused laswp (other 112 cols) + strip pre-update + 16-row TRSM.
// ---------------------------------------------------------------------------
__global__ __launch_bounds__(1024) void lu_panel(
    float* __restrict__ A, int k0, int ok0, int* __restrict__ piv)
{
  const int t = threadIdx.x;
  const int M = NN - k0;
  const int p16 = k0 - ok0;        // cols left of this panel inside outer block
  const int nq = p16 / NB;         // previous panels in this outer block
  float a[4][NB];
  __shared__ float rv[2][16]; __shared__ int ri[2][16];
  __shared__ float pb[2][NB];      // pivot row (double-buffered)
  __shared__ float bufA[2][NB];    // row-j stash (double-buffered)
  __shared__ int piv_s[NB];
  __shared__ int sd[32], ss[32];
  __shared__ float l16[16][17];
  __shared__ float us[16][17];     // U block for entry updates
  __shared__ float gbuf[32][112];

  // load panel cols into registers (row r = t + 1024*i)
  #pragma unroll
  for (int i = 0; i < 4; ++i) {
    int r = t + (i << 10);
    if (r < M) {
      const float* src = A + (size_t)(k0 + r) * NN + k0;
      #pragma unroll
      for (int c4 = 0; c4 < NB; c4 += 4) {
        float4 v = ldg4(src + c4);
        a[i][c4] = v.x; a[i][c4+1] = v.y; a[i][c4+2] = v.z; a[i][c4+3] = v.w;
      }
    }
  }

  // ---- entry: deferred updates from panels q < nq ----
  for (int q = 0; q < nq; ++q) {
    const int kq = ok0 + q * NB;
    if (t < 256) us[t >> 4][t & 15] = A[(size_t)(kq + (t >> 4)) * NN + k0 + (t & 15)];
    __syncthreads();
    #pragma unroll
    for (int i = 0; i < 4; ++i) {
      int r = t + (i << 10);
      if (r < M) {
        const float* lp = A + (size_t)(k0 + r) * NN + kq;
        float l[16];
        #pragma unroll
        for (int c4 = 0; c4 < NB; c4 += 4) {
          float4 v = ldg4(lp + c4);
          l[c4] = v.x; l[c4+1] = v.y; l[c4+2] = v.z; l[c4+3] = v.w;
        }
        #pragma unroll
        for (int c = 0; c < NB; ++c) {
          float s = 0.f;
          #pragma unroll
          for (int k = 0; k < NB; ++k) s += l[k] * us[k][c];
          a[i][c] -= s;
        }
      }
    }
    __syncthreads();
  }

  // ---- factorization: 2 barriers per column ----
  #pragma unroll
  for (int j = 0; j < NB; ++j) {
    const int bb = j & 1;
    // pivot search over rows r >= j
    float bv = -1.0f; int br = 1 << 30;
    #pragma unroll
    for (int i = 0; i < 4; ++i) {
      int r = t + (i << 10);
      if (r >= j && r < M) {
        float v = fabsf(a[i][j]);
        if (v > bv || (v == bv && r < br)) { bv = v; br = r; }
      }
    }
    for (int off = 32; off; off >>= 1) {
      float ov = __shfl_down(bv, off); int orr = __shfl_down(br, off);
      if (ov > bv || (ov == bv && orr < br)) { bv = ov; br = orr; }
    }
    if ((t & 63) == 0) { rv[bb][t >> 6] = bv; ri[bb][t >> 6] = br; }
    __syncthreads();                        // B1
    // all-thread parallel final scan of 16 wave results
    float fv = rv[bb][0]; int fr = ri[bb][0];
    #pragma unroll
    for (int w = 1; w < 16; ++w)
      if (rv[bb][w] > fv || (rv[bb][w] == fv && ri[bb][w] < fr)) { fv = rv[bb][w]; fr = ri[bb][w]; }
    const int pr = fr;
    if (t == 0) piv_s[j] = k0 + pr;
    const int prT = pr & 1023, prS = pr >> 10;
    if (t == prT) {
      #pragma unroll
      for (int i2 = 0; i2 < 4; ++i2) if (i2 == prS) {
        #pragma unroll
        for (int c = 0; c < NB; ++c) pb[bb][c] = a[i2][c];
      }
    }
    if (t == j) {
      #pragma unroll
      for (int c = 0; c < NB; ++c) bufA[bb][c] = a[0][c];
    }
    __syncthreads();                        // B2
    if (t == j) {
      #pragma unroll
      for (int c = 0; c < NB; ++c) a[0][c] = pb[bb][c];
    }
    if (t == prT) {
      #pragma unroll
      for (int i2 = 0; i2 < 4; ++i2) if (i2 == prS) {
        #pragma unroll
        for (int c = 0; c < NB; ++c) a[i2][c] = bufA[bb][c];
      }
    }
    // scale + rank-1 update (pb[bb] = pivot row)
    float rp = 1.0f / pb[bb][j];
    #pragma unroll
    for (int i = 0; i < 4; ++i) {
      int r = t + (i << 10);
      if (r > j && r < M) {
        float mlt = a[i][j] * rp;
        a[i][j] = mlt;
        #pragma unroll
        for (int c = j + 1; c < NB; ++c) a[i][c] -= mlt * pb[bb][c];
      }
    }
    // no trailing barrier: next column uses the other LDS buffers
  }
  __syncthreads();

  // writeback panel cols
  #pragma unroll
  for (int i = 0; i < 4; ++i) {
    int r = t + (i << 10);
    if (r < M) {
      float* dst = A + (size_t)(k0 + r) * NN + k0;
      #pragma unroll
      for (int c4 = 0; c4 < NB; c4 += 4)
        *(float4*)(dst + c4) = make_float4(a[i][c4], a[i][c4+1], a[i][c4+2], a[i][c4+3]);
    }
  }
  if (t < NB) piv[k0 + t] = piv_s[t];

  // stash L16 (threads t<16 hold final local row t in a[0][:])
  if (t < 16) {
    #pragma unroll
    for (int c2 = 0; c2 < NB; ++c2) l16[t][c2] = a[0][c2];
  }

  // net-permutation simulation on wave 0 (<=32 touched slots for NB=16)
  if (t < 32) {
    int slotrow = (t < NB) ? (k0 + t) : -1;
    int content = slotrow;
    int next_ext = NB;
    for (int j = 0; j < NB; ++j) {
      int p = piv_s[j];
      unsigned long long mask = __ballot(slotrow == p);
      int bslot;
      if (mask) bslot = __ffsll((unsigned long long)mask) - 1;
      else {
        bslot = next_ext;
        if (t == next_ext) { slotrow = p; content = p; }
        next_ext++;
      }
      int srcl = (t == j) ? bslot : ((t == bslot) ? j : t);
      content = __shfl(content, srcl);
    }
    sd[t] = slotrow;   // -1 for unused slots
    ss[t] = content;
  }
  __syncthreads();

  // fused laswp on the other 112 cols of the outer panel [ok0, ok0+OB)
  for (int idx = t; idx < 32 * 112; idx += 1024) {
    int i = idx / 112, cc = idx - i * 112;
    if (sd[i] >= 0 && sd[i] != ss[i]) {
      int c = ok0 + (cc < p16 ? cc : cc + NB);
      gbuf[i][cc] = A[(size_t)ss[i] * NN + c];
    }
  }
  __syncthreads();
  for (int idx = t; idx < 32 * 112; idx += 1024) {
    int i = idx / 112, cc = idx - i * 112;
    if (sd[i] >= 0 && sd[i] != ss[i]) {
      int c = ok0 + (cc < p16 ? cc : cc + NB);
      A[(size_t)sd[i] * NN + c] = gbuf[i][cc];
    }
  }
  __syncthreads();

  // ---- strip: deferred updates (q < nq) + trsm16 on cols [k0+16, ok0+128) ----
  const int w = ok0 + OB - (k0 + NB);   // 112 - p16, can be 0
  if (w > 0) {
    const int c = k0 + NB + t;
    const int cc = p16 + t;              // laswp col-enum index for c
    const bool own = (t < w);
    float x[16];
    if (own) {
      #pragma unroll
      for (int i = 0; i < 16; ++i)
        x[i] = (ss[i] != sd[i]) ? gbuf[i][cc] : A[(size_t)(k0 + i) * NN + c];
    }
    for (int q = 0; q < nq; ++q) {
      const int kq = ok0 + q * NB;
      // lq[i][k] = final L value at row k0+i, col kq+k (post-swap)
      if (t < 256) {
        int i = t >> 4, k = t & 15;
        us[i][k] = (ss[i] != sd[i]) ? gbuf[i][16 * q + k]
                                    : A[(size_t)(k0 + i) * NN + kq + k];
      }
      __syncthreads();
      if (own) {
        float uv[16];
        #pragma unroll
        for (int k = 0; k < 16; ++k) uv[k] = A[(size_t)(kq + k) * NN + c];
        #pragma unroll
        for (int i = 0; i < 16; ++i) {
          float s = 0.f;
          #pragma unroll
          for (int k = 0; k < 16; ++k) s += us[i][k] * uv[k];
          x[i] -= s;
        }
      }
      __syncthreads();
    }
    if (own) {
      #pragma unroll
      for (int i = 1; i < 16; ++i)
        #pragma unroll
        for (int j = 0; j < i; ++j) x[i] -= l16[i][j] * x[j];
      #pragma unroll
      for (int i = 0; i < 16; ++i) A[(size_t)(k0 + i) * NN + c] = x[i];
    }
  }
}

// ---------------------------------------------------------------------------
// 7) compose 128 pivots of an outer block into a net permutation (<=256 slots).
//    Single wave, shuffle-based, zero barriers in the loop.
// ---------------------------------------------------------------------------
__global__ __launch_bounds__(64) void net_perm128(
    const int* __restrict__ piv_g, int ok0,
    int* __restrict__ nd, int* __restrict__ ns)
{
  __shared__ int pl[OB];
  const int L = threadIdx.x;  // 0..63
  pl[L] = piv_g[ok0 + L];
  pl[L + 64] = piv_g[ok0 + 64 + L];
  __syncthreads();
  // lane L owns slots: L (plane0), 64+L (plane1) in-block; 128+L, 192+L external
  int c0 = ok0 + L, c1 = ok0 + 64 + L, c2 = -1, c3 = -1;  // contents
  int sr2 = -1, sr3 = -1;                                  // external slot addresses
  int next_ext = 128;
  for (int j = 0; j < OB; ++j) {
    int p = pl[j];
    int s2;
    if (p < ok0 + OB) s2 = p - ok0;
    else {
      unsigned long long m2 = __ballot(sr2 == p);
      unsigned long long m3 = __ballot(sr3 == p);
      if (m2) s2 = 128 + (__ffsll(m2) - 1);
      else if (m3) s2 = 192 + (__ffsll(m3) - 1);
      else {
        s2 = next_ext;
        if (s2 < 192) { if (L == s2 - 128) { sr2 = p; c2 = p; } }
        else          { if (L == s2 - 192) { sr3 = p; c3 = p; } }
        next_ext++;
      }
    }
    // swap contents of slot j (in-block) and slot s2
    int jp = j >> 6, jl = j & 63, sp = s2 >> 6, sl = s2 & 63;
    int vj0 = __shfl(c0, jl), vj1 = __shfl(c1, jl);
    int vj = (jp == 0) ? vj0 : vj1;
    int vs0 = __shfl(c0, sl), vs1 = __shfl(c1, sl), vs2 = __shfl(c2, sl), vs3 = __shfl(c3, sl);
    int vs = (sp == 0) ? vs0 : (sp == 1) ? vs1 : (sp == 2) ? vs2 : vs3;
    if (jp == 0 && L == jl) c0 = vs;
    if (jp == 1 && L == jl) c1 = vs;
    if (sp == 0 && L == sl) c0 = vj;
    if (sp == 1 && L == sl) c1 = vj;
    if (sp == 2 && L == sl) c2 = vj;
    if (sp == 3 && L == sl) c3 = vj;
  }
  nd[L] = ok0 + L;        ns[L] = c0;
  nd[64 + L] = ok0 + 64 + L; ns[64 + L] = c1;
  nd[128 + L] = sr2;      ns[128 + L] = c2;
  nd[192 + L] = sr3;      ns[192 + L] = c3;
}

// ---------------------------------------------------------------------------
// 8) apply net permutation to cols outside [ok0, ok0+128) via temp buffer.
// ---------------------------------------------------------------------------
__global__ __launch_bounds__(256) void perm_copy_out(
    const float* __restrict__ A, float* __restrict__ T,
    const int* __restrict__ nd, const int* __restrict__ ns, int ok0)
{
  int s = blockIdx.y;
  int d = nd[s], sr = ns[s];
  if (d < 0 || d == sr) return;
  int c = blockIdx.x * 1024 + threadIdx.x * 4;
  if (c >= ok0 && c < ok0 + OB) return;
  *(float4*)(T + (size_t)s * NN + c) = ldg4(A + (size_t)sr * NN + c);
}

__global__ __launch_bounds__(256) void perm_copy_in(
    float* __restrict__ A, const float* __restrict__ T,
    const int* __restrict__ nd, const int* __restrict__ ns, int ok0)
{
  int s = blockIdx.y;
  int d = nd[s], sr = ns[s];
  if (d < 0 || d == sr) return;
  int c = blockIdx.x * 1024 + threadIdx.x * 4;
  if (c >= ok0 && c < ok0 + OB) return;
  *(float4*)(A + (size_t)d * NN + c) = ldg4(T + (size_t)s * NN + c);
}

// ---------------------------------------------------------------------------
// 9) block TRSM: A[ok0:ok0+128, ok0+128:] = L11^{-1} @ same (unit lower 128).
//    xs padded to 133 (stride 5 mod 32 -> conflict-free); 4-accum partial sums.
// ---------------------------------------------------------------------------
__global__ __launch_bounds__(64) void trsm128L(float* __restrict__ A, int ok0)
{
  __shared__ float Ls[64][65];
  __shared__ float xs[64][133];
  const int t = threadIdx.x;
  const int c = ok0 + OB + blockIdx.x * 64 + t;
  for (int i = 0; i < 128; ++i) xs[t][i] = A[(size_t)(ok0 + i) * NN + c];
  // phase A: L00 (rows 0..63)
  for (int i = 0; i < 64; ++i) Ls[i][t] = A[(size_t)(ok0 + i) * NN + ok0 + t];
  __syncthreads();
  for (int i = 1; i < 64; ++i) {
    float s0 = 0.f, s1 = 0.f, s2 = 0.f, s3 = 0.f;
    int j = 0;
    for (; j + 3 < i; j += 4) {
      s0 += Ls[i][j+0] * xs[t][j+0]; s1 += Ls[i][j+1] * xs[t][j+1];
      s2 += Ls[i][j+2] * xs[t][j+2]; s3 += Ls[i][j+3] * xs[t][j+3];
    }
    for (; j < i; ++j) s0 += Ls[i][j] * xs[t][j];
    xs[t][i] -= (s0 + s1) + (s2 + s3);
  }
  __syncthreads();
  // phase B: L10 (rows 64..127, cols 0..63)
  for (int i = 0; i < 64; ++i) Ls[i][t] = A[(size_t)(ok0 + 64 + i) * NN + ok0 + t];
  __syncthreads();
  for (int i = 0; i < 64; ++i) {
    float s0 = 0.f, s1 = 0.f, s2 = 0.f, s3 = 0.f;
    #pragma unroll 4
    for (int j = 0; j < 64; j += 4) {
      s0 += Ls[i][j+0] * xs[t][j+0]; s1 += Ls[i][j+1] * xs[t][j+1];
      s2 += Ls[i][j+2] * xs[t][j+2]; s3 += Ls[i][j+3] * xs[t][j+3];
    }
    xs[t][64 + i] -= (s0 + s1) + (s2 + s3);
  }
  __syncthreads();
  // phase C: L11 (rows 64..127, cols 64..127)
  for (int i = 0; i < 64; ++i) Ls[i][t] = A[(size_t)(ok0 + 64 + i) * NN + ok0 + 64 + t];
  __syncthreads();
  for (int i = 1; i < 64; ++i) {
    float s0 = 0.f, s1 = 0.f, s2 = 0.f, s3 = 0.f;
    int j = 0;
    for (; j + 3 < i; j += 4) {
      s0 += Ls[i][j+0] * xs[t][64+j+0]; s1 += Ls[i][j+1] * xs[t][64+j+1];
      s2 += Ls[i][j+2] * xs[t][64+j+2]; s3 += Ls[i][j+3] * xs[t][64+j+3];
    }
    for (; j < i; ++j) s0 += Ls[i][j] * xs[t][64+j];
    xs[t][64 + i] -= (s0 + s1) + (s2 + s3);
  }
  for (int i = 0; i < 128; ++i) A[(size_t)(ok0 + i) * NN + c] = xs[t][i];
}

// ---------------------------------------------------------------------------
// 10) C -= Aop * Bop, 128x128 tile, 8x8 micro-tile, 256 threads.
//     NO bounds checks: Mr, Nc must be multiples of 128, K multiple of 16.
// ---------------------------------------------------------------------------
__global__ __launch_bounds__(256) void rank_update128(
    float* __restrict__ C, int ldc,
    const float* __restrict__ Aop, int lda,
    const float* __restrict__ Bop, int ldb,
    int K)
{
  __shared__ float As[16][132], Bs[16][132];
  const int m0 = blockIdx.x * 128, n0 = blockIdx.y * 128;
  const int t = threadIdx.x;
  const int tr = t >> 4, tc = t & 15;   // 16x16 thread grid, 8x8 each
  float acc[8][8] = {};
  for (int kb = 0; kb < K; kb += 16) {
    {
      int m = t >> 1, k8 = (t & 1) << 3;   // 128 rows x 16 k, 2 thr/row
      const float* ap = Aop + (size_t)(m0 + m) * lda + kb + k8;
      float4 v0 = ldg4(ap), v1 = ldg4(ap + 4);
      As[k8+0][m] = v0.x; As[k8+1][m] = v0.y; As[k8+2][m] = v0.z; As[k8+3][m] = v0.w;
      As[k8+4][m] = v1.x; As[k8+5][m] = v1.y; As[k8+6][m] = v1.z; As[k8+7][m] = v1.w;
    }
    {
      int kr = t >> 4, c8 = (t & 15) << 3; // 16 k x 128 cols
      const float* bp = Bop + (size_t)(kb + kr) * ldb + n0 + c8;
      *(float4*)&Bs[kr][c8]     = ldg4(bp);
      *(float4*)&Bs[kr][c8 + 4] = ldg4(bp + 4);
    }
    __syncthreads();
    #pragma unroll
    for (int k = 0; k < 16; ++k) {
      float av[8], bv[8];
      *(float4*)av       = *(const float4*)&As[k][tr << 3];
      *(float4*)(av + 4) = *(const float4*)&As[k][(tr << 3) + 4];
      *(float4*)bv       = *(const float4*)&Bs[k][tc << 3];
      *(float4*)(bv + 4) = *(const float4*)&Bs[k][(tc << 3) + 4];
      #pragma unroll
      for (int r = 0; r < 8; ++r)
        #pragma unroll
        for (int c = 0; c < 8; ++c) acc[r][c] += av[r] * bv[c];
    }
    __syncthreads();
  }
  #pragma unroll
  for (int r = 0; r < 8; ++r) {
    float* cp = C + (size_t)(m0 + (tr << 3) + r) * ldc + n0 + (tc << 3);
    float4 c0 = *(float4*)cp, c1 = *(float4*)(cp + 4);
    c0.x -= acc[r][0]; c0.y -= acc[r][1]; c0.z -= acc[r][2]; c0.w -= acc[r][3];
    c1.x -= acc[r][4]; c1.y -= acc[r][5]; c1.z -= acc[r][6]; c1.w -= acc[r][7];
    *(float4*)cp = c0; *(float4*)(cp + 4) = c1;
  }
}

// ---------------------------------------------------------------------------
// 11) invert the 32 diagonal 128x128 blocks of L (unit lower) / U (upper).
// ---------------------------------------------------------------------------
__global__ __launch_bounds__(128) void inv_tri(
    const float* __restrict__ Ag, float* __restrict__ invT, int upper)
{
  __shared__ float xs[128][128];
  const int s = blockIdx.x, t = threadIdx.x;
  const size_t r0 = (size_t)s * SB;
  for (int i = 0; i < 128; ++i) xs[i][t] = 0.0f;
  const float* Tb = Ag + r0 * NN + r0;
  if (!upper) {
    xs[t][t] = 1.0f;
    for (int i = 1; i < 128; ++i) {
      float s0 = 0.f, s1 = 0.f, s2 = 0.f, s3 = 0.f;
      int j = 0;
      for (; j + 3 < i; j += 4) {
        s0 += Tb[(size_t)i * NN + j+0] * xs[j+0][t];
        s1 += Tb[(size_t)i * NN + j+1] * xs[j+1][t];
        s2 += Tb[(size_t)i * NN + j+2] * xs[j+2][t];
        s3 += Tb[(size_t)i * NN + j+3] * xs[j+3][t];
      }
      for (; j < i; ++j) s0 += Tb[(size_t)i * NN + j] * xs[j][t];
      float ssum = (s0 + s1) + (s2 + s3);
      if (i != t) xs[i][t] = -ssum;
    }
  } else {
    xs[t][t] = 1.0f / Tb[(size_t)t * NN + t];
    for (int i = 126; i >= 0; --i) {
      float s0 = 0.f, s1 = 0.f, s2 = 0.f, s3 = 0.f;
      int j = i + 1;
      for (; j + 3 < 128; j += 4) {
        s0 += Tb[(size_t)i * NN + j+0] * xs[j+0][t];
        s1 += Tb[(size_t)i * NN + j+1] * xs[j+1][t];
        s2 += Tb[(size_t)i * NN + j+2] * xs[j+2][t];
        s3 += Tb[(size_t)i * NN + j+3] * xs[j+3][t];
      }
      for (; j < 128; ++j) s0 += Tb[(size_t)i * NN + j] * xs[j][t];
      float ssum = (s0 + s1) + (s2 + s3);
      if (i != t) xs[i][t] = -ssum / Tb[(size_t)i * NN + i];
    }
  }
  for (int i = 0; i < 128; ++i) invT[(size_t)s * SB * SB + (size_t)i * SB + t] = xs[i][t];
}

// ---------------------------------------------------------------------------
// 12) compose pivot swaps into a gather permutation idxp.
// ---------------------------------------------------------------------------
__global__ __launch_bounds__(1024) void perm_compose(
    const int* __restrict__ piv, int* __restrict__ idxp)
{
  __shared__ int pl[NN];
  const int t = threadIdx.x;
  for (int j = t; j < NN; j += 1024) pl[j] = piv[j];
  __syncthreads();
  int pos[4] = { t, t + 1024, t + 2048, t + 3072 };
  for (int j = NN - 1; j >= 0; --j) {
    int p = pl[j];
    #pragma unroll
    for (int u = 0; u < 4; ++u) {
      int r = t + (u << 10);
      if (j <= r) {
        if (pos[u] == j) pos[u] = p;
        else if (pos[u] == p) pos[u] = j;
      }
    }
  }
  #pragma unroll
  for (int u = 0; u < 4; ++u) idxp[t + (u << 10)] = pos[u];
}

// 13) out[r][:] = xf[idxp[r]][:]
__global__ __launch_bounds__(256) void gather_rows(
    const float* __restrict__ xf, const int* __restrict__ idxp, float* __restrict__ out)
{
  const int r = blockIdx.x, t = threadIdx.x;
  const int src = idxp[r];
  const float4* s = (const float4*)(xf + (size_t)src * DD);
  float4* d = (float4*)(out + (size_t)r * DD);
  for (int c = t; c < DD / 4; c += 256) d[c] = s[c];
}

// ---------------------------------------------------------------------------
// 14) in-place diag block apply: B[r0:r0+128, :] = Minv(128x128) @ same.
// ---------------------------------------------------------------------------
__global__ __launch_bounds__(256) void diag_apply(
    float* __restrict__ B, const float* __restrict__ Minv, int r0)
{
  __shared__ float Bs[128][68];
  const int c0 = blockIdx.x * 64, t = threadIdx.x;
  #pragma unroll
  for (int v = 0; v < 8; ++v) {
    int id = t + v * 256;
    int k = id >> 4, c4 = (id & 15) << 2;
    *(float4*)&Bs[k][c4] = ldg4(B + (size_t)(r0 + k) * DD + c0 + c4);
  }
  __syncthreads();
  const int tr = t >> 4, tc = t & 15;
  float acc[8][4] = {};
  for (int k4 = 0; k4 < 128; k4 += 4) {
    float b0[4], b1[4], b2[4], b3[4];
    *(float4*)b0 = *(const float4*)&Bs[k4+0][tc << 2];
    *(float4*)b1 = *(const float4*)&Bs[k4+1][tc << 2];
    *(float4*)b2 = *(const float4*)&Bs[k4+2][tc << 2];
    *(float4*)b3 = *(const float4*)&Bs[k4+3][tc << 2];
    #pragma unroll
    for (int rr = 0; rr < 8; ++rr) {
      float m[4]; *(float4*)m = ldg4(Minv + (size_t)(tr*8 + rr) * SB + k4);
      #pragma unroll
      for (int c = 0; c < 4; ++c)
        acc[rr][c] += m[0]*b0[c] + m[1]*b1[c] + m[2]*b2[c] + m[3]*b3[c];
    }
  }
  #pragma unroll
  for (int rr = 0; rr < 8; ++rr)
    *(float4*)(B + (size_t)(r0 + tr*8 + rr) * DD + c0 + (tc << 2)) =
        make_float4(acc[rr][0], acc[rr][1], acc[rr][2], acc[rr][3]);
}

// ---------------------------------------------------------------------------
extern "C" void kernel_launch(void* const* d_in, const int* in_sizes, int n_in,
                              void* d_out, int out_size, void* d_ws, size_t ws_size,
                              hipStream_t stream)
{
  const float* xf    = (const float*)d_in[0];
  const float* Wq    = (const float*)d_in[1];
  const float* Wk    = (const float*)d_in[2];
  const float* alpha = (const float*)d_in[3];
  float* out = (float*)d_out;
  char* ws = (char*)d_ws;

  // workspace layout (~90.3 MB)
  float* Amat = (float*)(ws);                          // 64 MB  (dots -> A -> LU)
  float* q    = (float*)(ws + 67108864ull);            // 8 MB (dead after dots_gemm)
  float* kbuf = (float*)(ws + 75497472ull);            // 8 MB
  float* invL = (float*)(ws + 83886080ull);            // 2 MB
  float* invU = (float*)(ws + 85983232ull);            // 2 MB
  unsigned int* bits = (unsigned int*)(ws + 88080384ull); // 2 MB
  float* q2   = (float*)(ws + 90177536ull);
  float* k2   = (float*)(ws + 90193920ull);
  int* piv    = (int*)(ws + 90210304ull);
  int* idxp   = (int*)(ws + 90226688ull);
  int* nd     = (int*)(ws + 90243072ull);              // 256 ints
  int* ns     = (int*)(ws + 90275840ull);              // 256 ints
  float* Tbuf = q;                                     // 4 MB perm temp (reuses q)

  proj_gemm<<<dim3(NN/64, DE/64), 256, 0, stream>>>(xf, Wq, Wk, q, kbuf);
  rownorm<<<2 * NN / 4, 256, 0, stream>>>(q, kbuf, q2, k2);
  dots_gemm<<<dim3(NN/64, NN/64), 256, 0, stream>>>(q, kbuf, q2, k2, Amat);
  topk_bits<<<NN, 256, 0, stream>>>(Amat, bits);
  build_A<<<NN * NN / 4 / 256, 256, 0, stream>>>(Amat, bits, alpha);

  // Two-level blocked LU, left-looking within each outer block (OB=128, NB=16).
  for (int ob = 0; ob < NOB; ++ob) {
    const int ok0 = ob * OB;
    for (int p = 0; p < OB / NB; ++p) {
      const int k0 = ok0 + p * NB;
      lu_panel<<<1, 1024, 0, stream>>>(Amat, k0, ok0, piv);
    }
    // apply the 128-step composed permutation to cols outside the panel
    net_perm128<<<1, 64, 0, stream>>>(piv, ok0, nd, ns);
    perm_copy_out<<<dim3(NN / 1024, 256), 256, 0, stream>>>(Amat, Tbuf, nd, ns, ok0);
    perm_copy_in<<<dim3(NN / 1024, 256), 256, 0, stream>>>(Amat, Tbuf, nd, ns, ok0);
    const int b1 = ok0 + OB;
    const int M2 = NN - b1;
    if (M2 > 0) {
      trsm128L<<<M2 / 64, 64, 0, stream>>>(Amat, ok0);
      rank_update128<<<dim3(M2 / 128, M2 / 128), 256, 0, stream>>>(
          Amat + (size_t)b1 * NN + b1, NN,
          Amat + (size_t)b1 * NN + ok0, NN,
          Amat + (size_t)ok0 * NN + b1, NN,
          OB);
    }
  }

  inv_tri<<<NSB, 128, 0, stream>>>(Amat, invL, 0);
  inv_tri<<<NSB, 128, 0, stream>>>(Amat, invU, 1);
  perm_compose<<<1, 1024, 0, stream>>>(piv, idxp);
  gather_rows<<<NN, 256, 0, stream>>>(xf, idxp, out);

  // forward solve L y = P b  (right-looking, block 128)
  for (int s = 0; s < NSB; ++s) {
    int r0 = s * SB;
    diag_apply<<<DD / 64, 256, 0, stream>>>(out, invL + (size_t)s * SB * SB, r0);
    if (r0 + SB < NN) {
      int M2 = NN - r0 - SB;
      rank_update128<<<dim3(M2 / 128, DD / 128), 256, 0, stream>>>(
          out + (size_t)(r0 + SB) * DD, DD,
          Amat + (size_t)(r0 + SB) * NN + r0, NN,
          out + (size_t)r0 * DD, DD,
          SB);
    }
  }
  // backward solve U x = y
  for (int s = NSB - 1; s >= 0; --s) {
    int r0 = s * SB;
    diag_apply<<<DD / 64, 256, 0, stream>>>(out, invU + (size_t)s * SB * SB, r0);
    if (r0 > 0) {
      rank_update128<<<dim3(r0 / 128, DD / 128), 256, 0, stream>>>(
          out, DD,
          Amat + r0, NN,
          out + (size_t)r0 * DD, DD,
          SB);
    }
  }
}

// Round 6
// 39500.491 us; speedup vs baseline: 1.3187x; 1.3187x over previous
//
#include <hip/hip_runtime.h>
#include <float.h>

// Problem constants (fixed shapes from setup_inputs)
#define NN 4096      // b*n
#define DD 640       // d
#define DE 512       // embed/inner dim
#define NB 16        // LU inner panel width
#define OB 128       // LU outer block width
#define NOB (NN/OB)  // 32 outer blocks
#define SB 128       // solve block
#define NSB (NN/SB)  // 32 solve blocks

static __device__ __forceinline__ float4 ldg4(const float* p) { return *(const float4*)p; }

// ---------------------------------------------------------------------------
// 1) q = xe@Wq, k = xe@Wk  (xe = xf[:, :512], ld 640). Fused dual GEMM.
// ---------------------------------------------------------------------------
__global__ __launch_bounds__(256) void proj_gemm(
    const float* __restrict__ xf, const float* __restrict__ Wq,
    const float* __restrict__ Wk, float* __restrict__ q, float* __restrict__ kk_)
{
  __shared__ float Xs[32][68], Qs[32][68], Ks[32][68];
  const int i0 = blockIdx.x * 64, c0 = blockIdx.y * 64;
  const int t = threadIdx.x, tr = t >> 4, tc = t & 15;
  float accq[4][4] = {}, acck[4][4] = {};
  for (int kb = 0; kb < DE; kb += 32) {
    {
      int m = t >> 3, k4 = (t & 7) << 2;
      float4 v0 = ldg4(xf + (size_t)(i0 + m) * DD + kb + k4);
      float4 v1 = ldg4(xf + (size_t)(i0 + m + 32) * DD + kb + k4);
      Xs[k4+0][m] = v0.x; Xs[k4+1][m] = v0.y; Xs[k4+2][m] = v0.z; Xs[k4+3][m] = v0.w;
      Xs[k4+0][m+32] = v1.x; Xs[k4+1][m+32] = v1.y; Xs[k4+2][m+32] = v1.z; Xs[k4+3][m+32] = v1.w;
    }
    {
      int kr = t >> 3, n8 = (t & 7) << 3;
      *(float4*)&Qs[kr][n8]   = ldg4(Wq + (size_t)(kb + kr) * DE + c0 + n8);
      *(float4*)&Qs[kr][n8+4] = ldg4(Wq + (size_t)(kb + kr) * DE + c0 + n8 + 4);
      *(float4*)&Ks[kr][n8]   = ldg4(Wk + (size_t)(kb + kr) * DE + c0 + n8);
      *(float4*)&Ks[kr][n8+4] = ldg4(Wk + (size_t)(kb + kr) * DE + c0 + n8 + 4);
    }
    __syncthreads();
    #pragma unroll
    for (int kkk = 0; kkk < 32; ++kkk) {
      float a[4], bq[4], bk[4];
      *(float4*)a  = *(const float4*)&Xs[kkk][tr << 2];
      *(float4*)bq = *(const float4*)&Qs[kkk][tc << 2];
      *(float4*)bk = *(const float4*)&Ks[kkk][tc << 2];
      #pragma unroll
      for (int r = 0; r < 4; ++r)
        #pragma unroll
        for (int c = 0; c < 4; ++c) { accq[r][c] += a[r]*bq[c]; acck[r][c] += a[r]*bk[c]; }
    }
    __syncthreads();
  }
  #pragma unroll
  for (int r = 0; r < 4; ++r) {
    float* qp = q   + (size_t)(i0 + (tr<<2) + r) * DE + c0 + (tc<<2);
    float* kp = kk_ + (size_t)(i0 + (tr<<2) + r) * DE + c0 + (tc<<2);
    *(float4*)qp = make_float4(accq[r][0], accq[r][1], accq[r][2], accq[r][3]);
    *(float4*)kp = make_float4(acck[r][0], acck[r][1], acck[r][2], acck[r][3]);
  }
}

// ---------------------------------------------------------------------------
// 2) row squared norms
// ---------------------------------------------------------------------------
__global__ __launch_bounds__(256) void rownorm(
    const float* __restrict__ q, const float* __restrict__ kk_,
    float* __restrict__ q2, float* __restrict__ k2)
{
  int w = (blockIdx.x * 256 + threadIdx.x) >> 6;
  int lane = threadIdx.x & 63;
  const float* src = (w < NN) ? q : kk_;
  int row = (w < NN) ? w : w - NN;
  const float* p = src + (size_t)row * DE;
  float s = 0.f;
  for (int c = lane; c < DE; c += 64) { float v = p[c]; s += v * v; }
  for (int off = 32; off; off >>= 1) s += __shfl_down(s, off);
  if (lane == 0) { if (w < NN) q2[row] = s; else k2[row] = s; }
}

// ---------------------------------------------------------------------------
// 3) dots = (q2[i]+k2[j]-2*q@k^T)/DE.  128x128 tile, 8x8 micro-tile
//    (same verified load/compute structure as rank_update128).
// ---------------------------------------------------------------------------
__global__ __launch_bounds__(256) void dots_gemm128(
    const float* __restrict__ q, const float* __restrict__ kk_,
    const float* __restrict__ q2, const float* __restrict__ k2,
    float* __restrict__ dots)
{
  __shared__ float As[16][132], Bs[16][132];
  const int i0 = blockIdx.x * 128, j0 = blockIdx.y * 128;
  const int t = threadIdx.x;
  const int tr = t >> 4, tc = t & 15;
  float acc[8][8] = {};
  for (int kb = 0; kb < DE; kb += 16) {
    {
      int m = t >> 1, k8 = (t & 1) << 3;   // 128 rows x 16 k, 2 thr/row
      const float* ap = q + (size_t)(i0 + m) * DE + kb + k8;
      float4 v0 = ldg4(ap), v1 = ldg4(ap + 4);
      As[k8+0][m] = v0.x; As[k8+1][m] = v0.y; As[k8+2][m] = v0.z; As[k8+3][m] = v0.w;
      As[k8+4][m] = v1.x; As[k8+5][m] = v1.y; As[k8+6][m] = v1.z; As[k8+7][m] = v1.w;
      const float* bp = kk_ + (size_t)(j0 + m) * DE + kb + k8;
      float4 w0 = ldg4(bp), w1 = ldg4(bp + 4);
      Bs[k8+0][m] = w0.x; Bs[k8+1][m] = w0.y; Bs[k8+2][m] = w0.z; Bs[k8+3][m] = w0.w;
      Bs[k8+4][m] = w1.x; Bs[k8+5][m] = w1.y; Bs[k8+6][m] = w1.z; Bs[k8+7][m] = w1.w;
    }
    __syncthreads();
    #pragma unroll
    for (int k = 0; k < 16; ++k) {
      float av[8], bv[8];
      *(float4*)av       = *(const float4*)&As[k][tr << 3];
      *(float4*)(av + 4) = *(const float4*)&As[k][(tr << 3) + 4];
      *(float4*)bv       = *(const float4*)&Bs[k][tc << 3];
      *(float4*)(bv + 4) = *(const float4*)&Bs[k][(tc << 3) + 4];
      #pragma unroll
      for (int r = 0; r < 8; ++r)
        #pragma unroll
        for (int c = 0; c < 8; ++c) acc[r][c] += av[r] * bv[c];
    }
    __syncthreads();
  }
  const float inv = 1.0f / (float)DE;
  float k2v[8];
  *(float4*)k2v       = ldg4(k2 + j0 + (tc << 3));
  *(float4*)(k2v + 4) = ldg4(k2 + j0 + (tc << 3) + 4);
  #pragma unroll
  for (int r = 0; r < 8; ++r) {
    float q2v = q2[i0 + (tr << 3) + r];
    float o[8];
    #pragma unroll
    for (int c = 0; c < 8; ++c) o[c] = (q2v + k2v[c] - 2.0f * acc[r][c]) * inv;
    float* dp = dots + (size_t)(i0 + (tr << 3) + r) * NN + j0 + (tc << 3);
    *(float4*)dp       = make_float4(o[0], o[1], o[2], o[3]);
    *(float4*)(dp + 4) = make_float4(o[4], o[5], o[6], o[7]);
  }
}

// ---------------------------------------------------------------------------
// 4) per-row top-64 -> bit mask rows
// ---------------------------------------------------------------------------
__global__ __launch_bounds__(256) void topk_bits(
    const float* __restrict__ dots, unsigned int* __restrict__ bits)
{
  __shared__ float row[NN];
  __shared__ unsigned int b[128];
  __shared__ float rv[4]; __shared__ int ri[4];
  const int i = blockIdx.x, t = threadIdx.x;
  const float* dr = dots + (size_t)i * NN;
  for (int c = t; c < NN; c += 256) row[c] = dr[c];
  if (t < 128) b[t] = 0u;
  __syncthreads();
  for (int it = 0; it < 64; ++it) {
    float bv = -FLT_MAX; int bi = NN;
    for (int c = t; c < NN; c += 256) { float v = row[c]; if (v > bv) { bv = v; bi = c; } }
    for (int off = 32; off; off >>= 1) {
      float ov = __shfl_down(bv, off); int oi = __shfl_down(bi, off);
      if (ov > bv || (ov == bv && oi < bi)) { bv = ov; bi = oi; }
    }
    if ((t & 63) == 0) { rv[t >> 6] = bv; ri[t >> 6] = bi; }
    __syncthreads();
    if (t == 0) {
      float fv = rv[0]; int fi = ri[0];
      for (int w = 1; w < 4; ++w)
        if (rv[w] > fv || (rv[w] == fv && ri[w] < fi)) { fv = rv[w]; fi = ri[w]; }
      b[fi >> 5] |= 1u << (fi & 31);
      row[fi] = -FLT_MAX;
    }
    __syncthreads();
  }
  if (t < 128) bits[(size_t)i * 128 + t] = b[t];
}

// ---------------------------------------------------------------------------
// 5) A = I - alpha * dots * (bit(i,j)|bit(j,i)), in place over dots.
// ---------------------------------------------------------------------------
__global__ __launch_bounds__(256) void build_A(
    float* __restrict__ A, const unsigned int* __restrict__ bits,
    const float* __restrict__ alpha_p)
{
  int tid = blockIdx.x * 256 + threadIdx.x;
  int i = tid >> 10;
  int j4 = (tid & 1023) << 2;
  float alpha = alpha_p[0];
  float* p = A + (size_t)i * NN + j4;
  float4 d = *(float4*)p;
  unsigned int wrow = bits[(size_t)i * 128 + (j4 >> 5)];
  float dv[4] = {d.x, d.y, d.z, d.w}, o[4];
  #pragma unroll
  for (int u = 0; u < 4; ++u) {
    int j = j4 + u;
    unsigned int m1 = (wrow >> (j & 31)) & 1u;
    unsigned int m2 = (bits[(size_t)j * 128 + (i >> 5)] >> (i & 31)) & 1u;
    float base = (i == j) ? 1.0f : 0.0f;
    o[u] = base - ((m1 | m2) ? alpha * dv[u] : 0.0f);
  }
  *(float4*)p = make_float4(o[0], o[1], o[2], o[3]);
}

// ---------------------------------------------------------------------------
// 6) LU panel (NB=16 cols), partial pivoting. 1024 threads.
//    Factor loop: 2 barriers/column (double-buffered rv/ri/pivot-row; the
//    verified r5 factor loop). Fused tail: laswp of the outer panel's other
//    112 cols + 16-row TRSM strip (the verified r4 tail).
// ---------------------------------------------------------------------------
__global__ __launch_bounds__(1024) void lu_panel(
    float* __restrict__ A, int k0, int ok0, int* __restrict__ piv)
{
  const int t = threadIdx.x;
  const int M = NN - k0;
  float a[4][NB];
  __shared__ float rv[2][16]; __shared__ int ri[2][16];
  __shared__ float pb[2][NB];      // pivot row (double-buffered)
  __shared__ float bufA[2][NB];    // row-j stash (double-buffered)
  __shared__ int piv_s[NB];
  __shared__ int sd[32], ss[32];
  __shared__ float l16[16][17];
  __shared__ float gbuf[32][112];

  // load panel cols into registers (row r = t + 1024*i)
  #pragma unroll
  for (int i = 0; i < 4; ++i) {
    int r = t + (i << 10);
    if (r < M) {
      const float* src = A + (size_t)(k0 + r) * NN + k0;
      #pragma unroll
      for (int c4 = 0; c4 < NB; c4 += 4) {
        float4 v = ldg4(src + c4);
        a[i][c4] = v.x; a[i][c4+1] = v.y; a[i][c4+2] = v.z; a[i][c4+3] = v.w;
      }
    }
  }

  // ---- factorization: 2 barriers per column ----
  #pragma unroll
  for (int j = 0; j < NB; ++j) {
    const int bb = j & 1;
    // pivot search over rows r >= j
    float bv = -1.0f; int br = 1 << 30;
    #pragma unroll
    for (int i = 0; i < 4; ++i) {
      int r = t + (i << 10);
      if (r >= j && r < M) {
        float v = fabsf(a[i][j]);
        if (v > bv || (v == bv && r < br)) { bv = v; br = r; }
      }
    }
    for (int off = 32; off; off >>= 1) {
      float ov = __shfl_down(bv, off); int orr = __shfl_down(br, off);
      if (ov > bv || (ov == bv && orr < br)) { bv = ov; br = orr; }
    }
    if ((t & 63) == 0) { rv[bb][t >> 6] = bv; ri[bb][t >> 6] = br; }
    __syncthreads();                        // B1
    // all-thread parallel final scan of 16 wave results
    float fv = rv[bb][0]; int fr = ri[bb][0];
    #pragma unroll
    for (int w = 1; w < 16; ++w)
      if (rv[bb][w] > fv || (rv[bb][w] == fv && ri[bb][w] < fr)) { fv = rv[bb][w]; fr = ri[bb][w]; }
    const int pr = fr;
    if (t == 0) piv_s[j] = k0 + pr;
    const int prT = pr & 1023, prS = pr >> 10;
    if (t == prT) {
      #pragma unroll
      for (int i2 = 0; i2 < 4; ++i2) if (i2 == prS) {
        #pragma unroll
        for (int c = 0; c < NB; ++c) pb[bb][c] = a[i2][c];
      }
    }
    if (t == j) {
      #pragma unroll
      for (int c = 0; c < NB; ++c) bufA[bb][c] = a[0][c];
    }
    __syncthreads();                        // B2
    if (t == j) {
      #pragma unroll
      for (int c = 0; c < NB; ++c) a[0][c] = pb[bb][c];
    }
    if (t == prT) {
      #pragma unroll
      for (int i2 = 0; i2 < 4; ++i2) if (i2 == prS) {
        #pragma unroll
        for (int c = 0; c < NB; ++c) a[i2][c] = bufA[bb][c];
      }
    }
    // scale + rank-1 update (pb[bb] = pivot row)
    float rp = 1.0f / pb[bb][j];
    #pragma unroll
    for (int i = 0; i < 4; ++i) {
      int r = t + (i << 10);
      if (r > j && r < M) {
        float mlt = a[i][j] * rp;
        a[i][j] = mlt;
        #pragma unroll
        for (int c = j + 1; c < NB; ++c) a[i][c] -= mlt * pb[bb][c];
      }
    }
    // no trailing barrier: next column uses the other LDS buffer set
  }
  __syncthreads();

  // writeback panel cols
  #pragma unroll
  for (int i = 0; i < 4; ++i) {
    int r = t + (i << 10);
    if (r < M) {
      float* dst = A + (size_t)(k0 + r) * NN + k0;
      #pragma unroll
      for (int c4 = 0; c4 < NB; c4 += 4)
        *(float4*)(dst + c4) = make_float4(a[i][c4], a[i][c4+1], a[i][c4+2], a[i][c4+3]);
    }
  }
  if (t < NB) piv[k0 + t] = piv_s[t];

  // stash L16 (threads t<16 hold final local row t in a[0][:])
  if (t < 16) {
    #pragma unroll
    for (int c2 = 0; c2 < NB; ++c2) l16[t][c2] = a[0][c2];
  }

  // net-permutation simulation on wave 0 (<=32 touched slots for NB=16)
  if (t < 32) {
    int slotrow = (t < NB) ? (k0 + t) : -1;
    int content = slotrow;
    int next_ext = NB;
    for (int j = 0; j < NB; ++j) {
      int p = piv_s[j];
      unsigned long long mask = __ballot(slotrow == p);
      int bslot;
      if (mask) bslot = __ffsll((unsigned long long)mask) - 1;
      else {
        bslot = next_ext;
        if (t == next_ext) { slotrow = p; content = p; }
        next_ext++;
      }
      int srcl = (t == j) ? bslot : ((t == bslot) ? j : t);
      content = __shfl(content, srcl);
    }
    sd[t] = slotrow;   // -1 for unused slots
    ss[t] = content;
  }
  __syncthreads();

  // fused laswp on the other 112 cols of the outer panel [ok0, ok0+OB)
  const int p16 = k0 - ok0;   // cols left of this 16-panel inside the outer panel
  for (int idx = t; idx < 32 * 112; idx += 1024) {
    int i = idx / 112, cc = idx - i * 112;
    if (sd[i] >= 0 && sd[i] != ss[i]) {
      int c = ok0 + (cc < p16 ? cc : cc + NB);
      gbuf[i][cc] = A[(size_t)ss[i] * NN + c];
    }
  }
  __syncthreads();
  for (int idx = t; idx < 32 * 112; idx += 1024) {
    int i = idx / 112, cc = idx - i * 112;
    if (sd[i] >= 0 && sd[i] != ss[i]) {
      int c = ok0 + (cc < p16 ? cc : cc + NB);
      A[(size_t)sd[i] * NN + c] = gbuf[i][cc];
    }
  }
  __syncthreads();

  // fused trsm16 tail on strip cols [k0+16, ok0+128)
  const int w = ok0 + OB - (k0 + NB);   // 112 - p16, can be 0
  if (t < w) {
    int c = k0 + NB + t;
    int cc = p16 + t;                    // laswp col-enum index for c
    float x[16];
    #pragma unroll
    for (int i = 0; i < 16; ++i)
      x[i] = (ss[i] != sd[i]) ? gbuf[i][cc] : A[(size_t)(k0 + i) * NN + c];
    #pragma unroll
    for (int i = 1; i < 16; ++i)
      #pragma unroll
      for (int j = 0; j < i; ++j) x[i] -= l16[i][j] * x[j];
    #pragma unroll
    for (int i = 0; i < 16; ++i) A[(size_t)(k0 + i) * NN + c] = x[i];
  }
}

// ---------------------------------------------------------------------------
// 7) compose 128 pivots of an outer block into a net permutation (<=256 slots).
//    Single wave, shuffle-based, zero barriers in the loop.
// ---------------------------------------------------------------------------
__global__ __launch_bounds__(64) void net_perm128(
    const int* __restrict__ piv_g, int ok0,
    int* __restrict__ nd, int* __restrict__ ns)
{
  __shared__ int pl[OB];
  const int L = threadIdx.x;  // 0..63
  pl[L] = piv_g[ok0 + L];
  pl[L + 64] = piv_g[ok0 + 64 + L];
  __syncthreads();
  // lane L owns slots: L (plane0), 64+L (plane1) in-block; 128+L, 192+L external
  int c0 = ok0 + L, c1 = ok0 + 64 + L, c2 = -1, c3 = -1;  // contents
  int sr2 = -1, sr3 = -1;                                  // external slot addresses
  int next_ext = 128;
  for (int j = 0; j < OB; ++j) {
    int p = pl[j];
    int s2;
    if (p < ok0 + OB) s2 = p - ok0;
    else {
      unsigned long long m2 = __ballot(sr2 == p);
      unsigned long long m3 = __ballot(sr3 == p);
      if (m2) s2 = 128 + (__ffsll(m2) - 1);
      else if (m3) s2 = 192 + (__ffsll(m3) - 1);
      else {
        s2 = next_ext;
        if (s2 < 192) { if (L == s2 - 128) { sr2 = p; c2 = p; } }
        else          { if (L == s2 - 192) { sr3 = p; c3 = p; } }
        next_ext++;
      }
    }
    // swap contents of slot j (in-block) and slot s2
    int jp = j >> 6, jl = j & 63, sp = s2 >> 6, sl = s2 & 63;
    int vj0 = __shfl(c0, jl), vj1 = __shfl(c1, jl);
    int vj = (jp == 0) ? vj0 : vj1;
    int vs0 = __shfl(c0, sl), vs1 = __shfl(c1, sl), vs2 = __shfl(c2, sl), vs3 = __shfl(c3, sl);
    int vs = (sp == 0) ? vs0 : (sp == 1) ? vs1 : (sp == 2) ? vs2 : vs3;
    if (jp == 0 && L == jl) c0 = vs;
    if (jp == 1 && L == jl) c1 = vs;
    if (sp == 0 && L == sl) c0 = vj;
    if (sp == 1 && L == sl) c1 = vj;
    if (sp == 2 && L == sl) c2 = vj;
    if (sp == 3 && L == sl) c3 = vj;
  }
  nd[L] = ok0 + L;        ns[L] = c0;
  nd[64 + L] = ok0 + 64 + L; ns[64 + L] = c1;
  nd[128 + L] = sr2;      ns[128 + L] = c2;
  nd[192 + L] = sr3;      ns[192 + L] = c3;
}

// ---------------------------------------------------------------------------
// 8) apply net permutation to cols outside [ok0, ok0+128) via temp buffer.
// ---------------------------------------------------------------------------
__global__ __launch_bounds__(256) void perm_copy_out(
    const float* __restrict__ A, float* __restrict__ T,
    const int* __restrict__ nd, const int* __restrict__ ns, int ok0)
{
  int s = blockIdx.y;
  int d = nd[s], sr = ns[s];
  if (d < 0 || d == sr) return;
  int c = blockIdx.x * 1024 + threadIdx.x * 4;
  if (c >= ok0 && c < ok0 + OB) return;
  *(float4*)(T + (size_t)s * NN + c) = ldg4(A + (size_t)sr * NN + c);
}

__global__ __launch_bounds__(256) void perm_copy_in(
    float* __restrict__ A, const float* __restrict__ T,
    const int* __restrict__ nd, const int* __restrict__ ns, int ok0)
{
  int s = blockIdx.y;
  int d = nd[s], sr = ns[s];
  if (d < 0 || d == sr) return;
  int c = blockIdx.x * 1024 + threadIdx.x * 4;
  if (c >= ok0 && c < ok0 + OB) return;
  *(float4*)(A + (size_t)d * NN + c) = ldg4(T + (size_t)s * NN + c);
}

// ---------------------------------------------------------------------------
// 9) block TRSM: A[ok0:ok0+128, ok0+128:] = L11^{-1} @ same (unit lower 128).
//    xs padded to 133 (stride 5 mod 32 -> conflict-free); 4-accum partial sums.
// ---------------------------------------------------------------------------
__global__ __launch_bounds__(64) void trsm128L(float* __restrict__ A, int ok0)
{
  __shared__ float Ls[64][65];
  __shared__ float xs[64][133];
  const int t = threadIdx.x;
  const int c = ok0 + OB + blockIdx.x * 64 + t;
  for (int i = 0; i < 128; ++i) xs[t][i] = A[(size_t)(ok0 + i) * NN + c];
  // phase A: L00 (rows 0..63)
  for (int i = 0; i < 64; ++i) Ls[i][t] = A[(size_t)(ok0 + i) * NN + ok0 + t];
  __syncthreads();
  for (int i = 1; i < 64; ++i) {
    float s0 = 0.f, s1 = 0.f, s2 = 0.f, s3 = 0.f;
    int j = 0;
    for (; j + 3 < i; j += 4) {
      s0 += Ls[i][j+0] * xs[t][j+0]; s1 += Ls[i][j+1] * xs[t][j+1];
      s2 += Ls[i][j+2] * xs[t][j+2]; s3 += Ls[i][j+3] * xs[t][j+3];
    }
    for (; j < i; ++j) s0 += Ls[i][j] * xs[t][j];
    xs[t][i] -= (s0 + s1) + (s2 + s3);
  }
  __syncthreads();
  // phase B: L10 (rows 64..127, cols 0..63)
  for (int i = 0; i < 64; ++i) Ls[i][t] = A[(size_t)(ok0 + 64 + i) * NN + ok0 + t];
  __syncthreads();
  for (int i = 0; i < 64; ++i) {
    float s0 = 0.f, s1 = 0.f, s2 = 0.f, s3 = 0.f;
    #pragma unroll 4
    for (int j = 0; j < 64; j += 4) {
      s0 += Ls[i][j+0] * xs[t][j+0]; s1 += Ls[i][j+1] * xs[t][j+1];
      s2 += Ls[i][j+2] * xs[t][j+2]; s3 += Ls[i][j+3] * xs[t][j+3];
    }
    xs[t][64 + i] -= (s0 + s1) + (s2 + s3);
  }
  __syncthreads();
  // phase C: L11 (rows 64..127, cols 64..127)
  for (int i = 0; i < 64; ++i) Ls[i][t] = A[(size_t)(ok0 + 64 + i) * NN + ok0 + 64 + t];
  __syncthreads();
  for (int i = 1; i < 64; ++i) {
    float s0 = 0.f, s1 = 0.f, s2 = 0.f, s3 = 0.f;
    int j = 0;
    for (; j + 3 < i; j += 4) {
      s0 += Ls[i][j+0] * xs[t][64+j+0]; s1 += Ls[i][j+1] * xs[t][64+j+1];
      s2 += Ls[i][j+2] * xs[t][64+j+2]; s3 += Ls[i][j+3] * xs[t][64+j+3];
    }
    for (; j < i; ++j) s0 += Ls[i][j] * xs[t][64+j];
    xs[t][64 + i] -= (s0 + s1) + (s2 + s3);
  }
  for (int i = 0; i < 128; ++i) A[(size_t)(ok0 + i) * NN + c] = xs[t][i];
}

// ---------------------------------------------------------------------------
// 10a) generic in-place C -= Aop * Bop, 64x64 tile (bounds-checked; for
//      narrow inner updates).
// ---------------------------------------------------------------------------
__global__ __launch_bounds__(256) void rank_update(
    float* __restrict__ C, int ldc,
    const float* __restrict__ Aop, int lda,
    const float* __restrict__ Bop, int ldb,
    int Mr, int Nc, int K)
{
  __shared__ float As[16][68], Bs[16][68];
  const int m0 = blockIdx.x * 64, n0 = blockIdx.y * 64;
  const int t = threadIdx.x, tr = t >> 4, tc = t & 15;
  const float4 z4 = make_float4(0.f, 0.f, 0.f, 0.f);
  float acc[4][4] = {};
  for (int kb = 0; kb < K; kb += 16) {
    {
      int m = t >> 2, k4 = (t & 3) << 2;   // 64 rows x 16 k
      float4 v0 = (m0 + m < Mr) ? ldg4(Aop + (size_t)(m0 + m) * lda + kb + k4) : z4;
      As[k4+0][m] = v0.x; As[k4+1][m] = v0.y; As[k4+2][m] = v0.z; As[k4+3][m] = v0.w;
    }
    {
      int kr = t >> 4, n4 = (t & 15) << 2; // 16 k x 64 cols
      bool ok = (n0 + n4 < Nc);
      float4 w0 = ok ? ldg4(Bop + (size_t)(kb + kr) * ldb + n0 + n4) : z4;
      *(float4*)&Bs[kr][n4] = w0;
    }
    __syncthreads();
    #pragma unroll
    for (int kkk = 0; kkk < 16; ++kkk) {
      float a[4], b[4];
      *(float4*)a = *(const float4*)&As[kkk][tr << 2];
      *(float4*)b = *(const float4*)&Bs[kkk][tc << 2];
      #pragma unroll
      for (int r = 0; r < 4; ++r)
        #pragma unroll
        for (int c = 0; c < 4; ++c) acc[r][c] += a[r] * b[c];
    }
    __syncthreads();
  }
  #pragma unroll
  for (int r = 0; r < 4; ++r) {
    int m = m0 + (tr << 2) + r;
    int n = n0 + (tc << 2);
    if (m < Mr && n < Nc) {
      float* cp = C + (size_t)m * ldc + n;
      float4 cv = *(float4*)cp;
      cv.x -= acc[r][0]; cv.y -= acc[r][1]; cv.z -= acc[r][2]; cv.w -= acc[r][3];
      *(float4*)cp = cv;
    }
  }
}

// ---------------------------------------------------------------------------
// 10b) C -= Aop * Bop, 128x128 tile, 8x8 micro-tile, 256 threads.
//      NO bounds checks: Mr, Nc must be multiples of 128, K multiple of 16.
// ---------------------------------------------------------------------------
__global__ __launch_bounds__(256) void rank_update128(
    float* __restrict__ C, int ldc,
    const float* __restrict__ Aop, int lda,
    const float* __restrict__ Bop, int ldb,
    int K)
{
  __shared__ float As[16][132], Bs[16][132];
  const int m0 = blockIdx.x * 128, n0 = blockIdx.y * 128;
  const int t = threadIdx.x;
  const int tr = t >> 4, tc = t & 15;   // 16x16 thread grid, 8x8 each
  float acc[8][8] = {};
  for (int kb = 0; kb < K; kb += 16) {
    {
      int m = t >> 1, k8 = (t & 1) << 3;   // 128 rows x 16 k, 2 thr/row
      const float* ap = Aop + (size_t)(m0 + m) * lda + kb + k8;
      float4 v0 = ldg4(ap), v1 = ldg4(ap + 4);
      As[k8+0][m] = v0.x; As[k8+1][m] = v0.y; As[k8+2][m] = v0.z; As[k8+3][m] = v0.w;
      As[k8+4][m] = v1.x; As[k8+5][m] = v1.y; As[k8+6][m] = v1.z; As[k8+7][m] = v1.w;
    }
    {
      int kr = t >> 4, c8 = (t & 15) << 3; // 16 k x 128 cols
      const float* bp = Bop + (size_t)(kb + kr) * ldb + n0 + c8;
      *(float4*)&Bs[kr][c8]     = ldg4(bp);
      *(float4*)&Bs[kr][c8 + 4] = ldg4(bp + 4);
    }
    __syncthreads();
    #pragma unroll
    for (int k = 0; k < 16; ++k) {
      float av[8], bv[8];
      *(float4*)av       = *(const float4*)&As[k][tr << 3];
      *(float4*)(av + 4) = *(const float4*)&As[k][(tr << 3) + 4];
      *(float4*)bv       = *(const float4*)&Bs[k][tc << 3];
      *(float4*)(bv + 4) = *(const float4*)&Bs[k][(tc << 3) + 4];
      #pragma unroll
      for (int r = 0; r < 8; ++r)
        #pragma unroll
        for (int c = 0; c < 8; ++c) acc[r][c] += av[r] * bv[c];
    }
    __syncthreads();
  }
  #pragma unroll
  for (int r = 0; r < 8; ++r) {
    float* cp = C + (size_t)(m0 + (tr << 3) + r) * ldc + n0 + (tc << 3);
    float4 c0 = *(float4*)cp, c1 = *(float4*)(cp + 4);
    c0.x -= acc[r][0]; c0.y -= acc[r][1]; c0.z -= acc[r][2]; c0.w -= acc[r][3];
    c1.x -= acc[r][4]; c1.y -= acc[r][5]; c1.z -= acc[r][6]; c1.w -= acc[r][7];
    *(float4*)cp = c0; *(float4*)(cp + 4) = c1;
  }
}

// ---------------------------------------------------------------------------
// 11) invert the 32 diagonal 128x128 blocks of L (unit lower) / U (upper).
// ---------------------------------------------------------------------------
__global__ __launch_bounds__(128) void inv_tri(
    const float* __restrict__ Ag, float* __restrict__ invT, int upper)
{
  __shared__ float xs[128][128];
  const int s = blockIdx.x, t = threadIdx.x;
  const size_t r0 = (size_t)s * SB;
  for (int i = 0; i < 128; ++i) xs[i][t] = 0.0f;
  const float* Tb = Ag + r0 * NN + r0;
  if (!upper) {
    xs[t][t] = 1.0f;
    for (int i = 1; i < 128; ++i) {
      float s0 = 0.f, s1 = 0.f, s2 = 0.f, s3 = 0.f;
      int j = 0;
      for (; j + 3 < i; j += 4) {
        s0 += Tb[(size_t)i * NN + j+0] * xs[j+0][t];
        s1 += Tb[(size_t)i * NN + j+1] * xs[j+1][t];
        s2 += Tb[(size_t)i * NN + j+2] * xs[j+2][t];
        s3 += Tb[(size_t)i * NN + j+3] * xs[j+3][t];
      }
      for (; j < i; ++j) s0 += Tb[(size_t)i * NN + j] * xs[j][t];
      float ssum = (s0 + s1) + (s2 + s3);
      if (i != t) xs[i][t] = -ssum;
    }
  } else {
    xs[t][t] = 1.0f / Tb[(size_t)t * NN + t];
    for (int i = 126; i >= 0; --i) {
      float s0 = 0.f, s1 = 0.f, s2 = 0.f, s3 = 0.f;
      int j = i + 1;
      for (; j + 3 < 128; j += 4) {
        s0 += Tb[(size_t)i * NN + j+0] * xs[j+0][t];
        s1 += Tb[(size_t)i * NN + j+1] * xs[j+1][t];
        s2 += Tb[(size_t)i * NN + j+2] * xs[j+2][t];
        s3 += Tb[(size_t)i * NN + j+3] * xs[j+3][t];
      }
      for (; j < 128; ++j) s0 += Tb[(size_t)i * NN + j] * xs[j][t];
      float ssum = (s0 + s1) + (s2 + s3);
      if (i != t) xs[i][t] = -ssum / Tb[(size_t)i * NN + i];
    }
  }
  for (int i = 0; i < 128; ++i) invT[(size_t)s * SB * SB + (size_t)i * SB + t] = xs[i][t];
}

// ---------------------------------------------------------------------------
// 12) compose pivot swaps into a gather permutation idxp.
// ---------------------------------------------------------------------------
__global__ __launch_bounds__(1024) void perm_compose(
    const int* __restrict__ piv, int* __restrict__ idxp)
{
  __shared__ int pl[NN];
  const int t = threadIdx.x;
  for (int j = t; j < NN; j += 1024) pl[j] = piv[j];
  __syncthreads();
  int pos[4] = { t, t + 1024, t + 2048, t + 3072 };
  for (int j = NN - 1; j >= 0; --j) {
    int p = pl[j];
    #pragma unroll
    for (int u = 0; u < 4; ++u) {
      int r = t + (u << 10);
      if (j <= r) {
        if (pos[u] == j) pos[u] = p;
        else if (pos[u] == p) pos[u] = j;
      }
    }
  }
  #pragma unroll
  for (int u = 0; u < 4; ++u) idxp[t + (u << 10)] = pos[u];
}

// 13) out[r][:] = xf[idxp[r]][:]
__global__ __launch_bounds__(256) void gather_rows(
    const float* __restrict__ xf, const int* __restrict__ idxp, float* __restrict__ out)
{
  const int r = blockIdx.x, t = threadIdx.x;
  const int src = idxp[r];
  const float4* s = (const float4*)(xf + (size_t)src * DD);
  float4* d = (float4*)(out + (size_t)r * DD);
  for (int c = t; c < DD / 4; c += 256) d[c] = s[c];
}

// ---------------------------------------------------------------------------
// 14) in-place diag block apply: B[r0:r0+128, :] = Minv(128x128) @ same.
// ---------------------------------------------------------------------------
__global__ __launch_bounds__(256) void diag_apply(
    float* __restrict__ B, const float* __restrict__ Minv, int r0)
{
  __shared__ float Bs[128][68];
  const int c0 = blockIdx.x * 64, t = threadIdx.x;
  #pragma unroll
  for (int v = 0; v < 8; ++v) {
    int id = t + v * 256;
    int k = id >> 4, c4 = (id & 15) << 2;
    *(float4*)&Bs[k][c4] = ldg4(B + (size_t)(r0 + k) * DD + c0 + c4);
  }
  __syncthreads();
  const int tr = t >> 4, tc = t & 15;
  float acc[8][4] = {};
  for (int k4 = 0; k4 < 128; k4 += 4) {
    float b0[4], b1[4], b2[4], b3[4];
    *(float4*)b0 = *(const float4*)&Bs[k4+0][tc << 2];
    *(float4*)b1 = *(const float4*)&Bs[k4+1][tc << 2];
    *(float4*)b2 = *(const float4*)&Bs[k4+2][tc << 2];
    *(float4*)b3 = *(const float4*)&Bs[k4+3][tc << 2];
    #pragma unroll
    for (int rr = 0; rr < 8; ++rr) {
      float m[4]; *(float4*)m = ldg4(Minv + (size_t)(tr*8 + rr) * SB + k4);
      #pragma unroll
      for (int c = 0; c < 4; ++c)
        acc[rr][c] += m[0]*b0[c] + m[1]*b1[c] + m[2]*b2[c] + m[3]*b3[c];
    }
  }
  #pragma unroll
  for (int rr = 0; rr < 8; ++rr)
    *(float4*)(B + (size_t)(r0 + tr*8 + rr) * DD + c0 + (tc << 2)) =
        make_float4(acc[rr][0], acc[rr][1], acc[rr][2], acc[rr][3]);
}

// ---------------------------------------------------------------------------
extern "C" void kernel_launch(void* const* d_in, const int* in_sizes, int n_in,
                              void* d_out, int out_size, void* d_ws, size_t ws_size,
                              hipStream_t stream)
{
  const float* xf    = (const float*)d_in[0];
  const float* Wq    = (const float*)d_in[1];
  const float* Wk    = (const float*)d_in[2];
  const float* alpha = (const float*)d_in[3];
  float* out = (float*)d_out;
  char* ws = (char*)d_ws;

  // workspace layout (~90.3 MB)
  float* Amat = (float*)(ws);                          // 64 MB  (dots -> A -> LU)
  float* q    = (float*)(ws + 67108864ull);            // 8 MB (dead after dots)
  float* kbuf = (float*)(ws + 75497472ull);            // 8 MB
  float* invL = (float*)(ws + 83886080ull);            // 2 MB
  float* invU = (float*)(ws + 85983232ull);            // 2 MB
  unsigned int* bits = (unsigned int*)(ws + 88080384ull); // 2 MB
  float* q2   = (float*)(ws + 90177536ull);
  float* k2   = (float*)(ws + 90193920ull);
  int* piv    = (int*)(ws + 90210304ull);
  int* idxp   = (int*)(ws + 90226688ull);
  int* nd     = (int*)(ws + 90243072ull);              // 256 ints
  int* ns     = (int*)(ws + 90275840ull);              // 256 ints
  float* Tbuf = q;                                     // 4 MB perm temp (reuses q)

  proj_gemm<<<dim3(NN/64, DE/64), 256, 0, stream>>>(xf, Wq, Wk, q, kbuf);
  rownorm<<<2 * NN / 4, 256, 0, stream>>>(q, kbuf, q2, k2);
  dots_gemm128<<<dim3(NN/128, NN/128), 256, 0, stream>>>(q, kbuf, q2, k2, Amat);
  topk_bits<<<NN, 256, 0, stream>>>(Amat, bits);
  build_A<<<NN * NN / 4 / 256, 256, 0, stream>>>(Amat, bits, alpha);

  // Two-level blocked LU with partial pivoting: outer OB=128, inner NB=16.
  for (int ob = 0; ob < NOB; ++ob) {
    const int ok0 = ob * OB;
    for (int p = 0; p < OB / NB; ++p) {
      const int k0 = ok0 + p * NB;
      lu_panel<<<1, 1024, 0, stream>>>(Amat, k0, ok0, piv);
      if (p < OB / NB - 1) {
        const int k1 = k0 + NB;
        const int w = ok0 + OB - k1;      // within-panel trailing cols
        const int M2 = NN - k1;
        rank_update<<<dim3((M2 + 63) / 64, (w + 63) / 64), 256, 0, stream>>>(
            Amat + (size_t)k1 * NN + k1, NN,
            Amat + (size_t)k1 * NN + k0, NN,
            Amat + (size_t)k0 * NN + k1, NN,
            M2, w, NB);
      }
    }
    // apply the 128-step composed permutation to cols outside the panel
    net_perm128<<<1, 64, 0, stream>>>(piv, ok0, nd, ns);
    perm_copy_out<<<dim3(NN / 1024, 256), 256, 0, stream>>>(Amat, Tbuf, nd, ns, ok0);
    perm_copy_in<<<dim3(NN / 1024, 256), 256, 0, stream>>>(Amat, Tbuf, nd, ns, ok0);
    const int b1 = ok0 + OB;
    const int M2 = NN - b1;
    if (M2 > 0) {
      trsm128L<<<M2 / 64, 64, 0, stream>>>(Amat, ok0);
      rank_update128<<<dim3(M2 / 128, M2 / 128), 256, 0, stream>>>(
          Amat + (size_t)b1 * NN + b1, NN,
          Amat + (size_t)b1 * NN + ok0, NN,
          Amat + (size_t)ok0 * NN + b1, NN,
          OB);
    }
  }

  inv_tri<<<NSB, 128, 0, stream>>>(Amat, invL, 0);
  inv_tri<<<NSB, 128, 0, stream>>>(Amat, invU, 1);
  perm_compose<<<1, 1024, 0, stream>>>(piv, idxp);
  gather_rows<<<NN, 256, 0, stream>>>(xf, idxp, out);

  // forward solve L y = P b  (right-looking, block 128)
  for (int s = 0; s < NSB; ++s) {
    int r0 = s * SB;
    diag_apply<<<DD / 64, 256, 0, stream>>>(out, invL + (size_t)s * SB * SB, r0);
    if (r0 + SB < NN) {
      int M2 = NN - r0 - SB;
      rank_update128<<<dim3(M2 / 128, DD / 128), 256, 0, stream>>>(
          out + (size_t)(r0 + SB) * DD, DD,
          Amat + (size_t)(r0 + SB) * NN + r0, NN,
          out + (size_t)r0 * DD, DD,
          SB);
    }
  }
  // backward solve U x = y
  for (int s = NSB - 1; s >= 0; --s) {
    int r0 = s * SB;
    diag_apply<<<DD / 64, 256, 0, stream>>>(out, invU + (size_t)s * SB * SB, r0);
    if (r0 > 0) {
      rank_update128<<<dim3(r0 / 128, DD / 128), 256, 0, stream>>>(
          out, DD,
          Amat + r0, NN,
          out + (size_t)r0 * DD, DD,
          SB);
    }
  }
}